// Round 10
// baseline (403.996 us; speedup 1.0000x reference)
//
#include <hip/hip_runtime.h>
#include <hip/hip_bf16.h>
#include <stdint.h>

#define NWIN 4096

typedef __attribute__((ext_vector_type(8))) short bf16x8;
typedef __attribute__((ext_vector_type(4))) float f32x4;

// ws layout (bytes):
//   wq  bf16 [768][256]  @0         (plain, row-major, = qkv_w cast)
//   wp  bf16 [256][256]  @393216
//   rb  f32  [8][16][64][4] @524288 ([h][kt>>2][qt][kt&3], *1/ln2, kt>=49 -> -1e30)
//   wsb f32  [768]       @655360    (qkv_b plain)
//   Q   bf16 [4096*8][49][32] @OFF_Q
//   K   bf16 ...          @OFF_K
//   V   bf16 ...          @OFF_V    (after attn, overwritten by OWS [200704][256] bf16)
#define OFF_WQ 0LL
#define OFF_WP 393216LL
#define OFF_RB 524288LL
#define OFF_B  655360LL
#define OFF_Q  1048576LL
#define QKV_STRIDE 102760448LL
#define OFF_K  (OFF_Q + QKV_STRIDE)
#define OFF_V  (OFF_Q + 2 * QKV_STRIDE)

static __device__ __forceinline__ uint32_t f2bf(float f) {
    union { float f; uint32_t u; } v; v.f = f;
    return (v.u + 0x7FFFu + ((v.u >> 16) & 1u)) >> 16;
}

static __device__ __forceinline__ uint32_t pk2(float lo, float hi) {
    union { __hip_bfloat162 h; uint32_t u; } c;
    c.h = __float22bfloat162_rn(float2{lo, hi});
    return c.u;
}

union FragU { uint32_t u[4]; bf16x8 v; };

// ---------------------------------------------------------------------------
// prep: weights fp32->bf16 (plain), rb gather (*1/ln2, kt>=49 -> -1e30), bias
// ---------------------------------------------------------------------------
__global__ void prep_kernel(const float* __restrict__ qkv_w, const float* __restrict__ proj_w,
                            const float* __restrict__ qkv_b,
                            const float* __restrict__ bias_table, const int* __restrict__ rel_index,
                            char* __restrict__ ws) {
    uint16_t* wq  = (uint16_t*)(ws + OFF_WQ);
    uint16_t* wp  = (uint16_t*)(ws + OFF_WP);
    float*    rb  = (float*)(ws + OFF_RB);
    float*    wsb = (float*)(ws + OFF_B);
    const int total = 196608 + 65536 + 32768 + 768;
    for (int idx = blockIdx.x * blockDim.x + threadIdx.x; idx < total;
         idx += gridDim.x * blockDim.x) {
        if (idx < 196608) {
            wq[idx] = (uint16_t)f2bf(qkv_w[idx]);
        } else if (idx < 262144) {
            int i = idx - 196608;
            wp[i] = (uint16_t)f2bf(proj_w[i]);
        } else if (idx < 294912) {
            int i = idx - 262144;                 // [h][kt4][qt][ii]
            int h = i >> 12, kt4 = (i >> 8) & 15, qt = (i >> 2) & 63, ii = i & 3;
            int kt = kt4 * 4 + ii;
            float v = -1e30f;
            if (kt < 49 && qt < 49)
                v = bias_table[rel_index[qt * 49 + kt] * 8 + h] * 1.4426950408889634f;
            rb[i] = v;
        } else {
            int n = idx - 294912;
            wsb[n] = qkv_b[n];
        }
    }
}

// ---------------------------------------------------------------------------
// qkv GEMM: [200704 x 768] = x[200704 x 256] @ wq^T, 128x128 tiles, BK=64.
// acc = mfma(B=weights, A=tokens): C row = n (4 consecutive), col = token.
// Epilogue: bias, C_LDS [tok][n] bf16, scatter to Q/K/V [b][h][49][32].
// ---------------------------------------------------------------------------
__global__ __launch_bounds__(256, 2) void qkv_kernel(const float* __restrict__ x,
                                                     char* __restrict__ ws) {
    __shared__ __align__(16) char smem[32768];
    uint16_t* A  = (uint16_t*)smem;             // [128][64] swz
    uint16_t* Bt = (uint16_t*)(smem + 16384);   // [128][64] swz
    const uint16_t* wq  = (const uint16_t*)(ws + OFF_WQ);
    const float*    wsb = (const float*)(ws + OFF_B);
    const int m0 = blockIdx.x * 128, n0 = blockIdx.y * 128;
    const int t = threadIdx.x, l = t & 63, w = t >> 6;
    const int lr = l & 15, lg = l >> 4;
    const int wm = w >> 1, wn = w & 1;
    f32x4 acc[4][4];
    #pragma unroll
    for (int a = 0; a < 4; ++a)
        #pragma unroll
        for (int b2 = 0; b2 < 4; ++b2) acc[a][b2] = (f32x4){0.f, 0.f, 0.f, 0.f};

    for (int kk = 0; kk < 4; ++kk) {
        #pragma unroll
        for (int it = 0; it < 4; ++it) {                 // A: x fp32 -> bf16, swz
            int item = it * 256 + t;
            int r = item >> 3, ch = item & 7;
            const float* src = x + (int64_t)(m0 + r) * 256 + kk * 64 + ch * 8;
            float4 v0 = *(const float4*)src;
            float4 v1 = *(const float4*)(src + 4);
            uint4 pk;
            pk.x = pk2(v0.x, v0.y); pk.y = pk2(v0.z, v0.w);
            pk.z = pk2(v1.x, v1.y); pk.w = pk2(v1.z, v1.w);
            *(uint4*)((char*)A + ((r * 128 + ch * 16) ^ ((r & 7) << 4))) = pk;
        }
        #pragma unroll
        for (int it = 0; it < 4; ++it) {                 // B: wq bf16, swz
            int item = it * 256 + t;
            int r = item >> 3, ch = item & 7;
            uint4 v = *(const uint4*)(wq + (int64_t)(n0 + r) * 256 + kk * 64 + ch * 8);
            *(uint4*)((char*)Bt + ((r * 128 + ch * 16) ^ ((r & 7) << 4))) = v;
        }
        __syncthreads();
        #pragma unroll
        for (int kh = 0; kh < 2; ++kh) {
            bf16x8 af[4], bfr[4];
            #pragma unroll
            for (int mi = 0; mi < 4; ++mi) {
                int r = wm * 64 + 16 * mi + lr;
                af[mi] = *(const bf16x8*)((char*)A + ((r * 128 + kh * 64 + lg * 16) ^ ((r & 7) << 4)));
            }
            #pragma unroll
            for (int nj = 0; nj < 4; ++nj) {
                int r = wn * 64 + 16 * nj + lr;
                bfr[nj] = *(const bf16x8*)((char*)Bt + ((r * 128 + kh * 64 + lg * 16) ^ ((r & 7) << 4)));
            }
            #pragma unroll
            for (int nj = 0; nj < 4; ++nj)
                #pragma unroll
                for (int mi = 0; mi < 4; ++mi)
                    acc[nj][mi] = __builtin_amdgcn_mfma_f32_16x16x32_bf16(bfr[nj], af[mi], acc[nj][mi], 0, 0, 0);
        }
        __syncthreads();
    }
    // epilogue: bias + C_LDS [128 tok][128 n] bf16 (overlay A/B), swz by tok
    uint16_t* C = (uint16_t*)smem;
    #pragma unroll
    for (int nj = 0; nj < 4; ++nj) {
        f32x4 bias = *(const f32x4*)(wsb + n0 + wn * 64 + 16 * nj + 4 * lg);
        #pragma unroll
        for (int mi = 0; mi < 4; ++mi) {
            int tok_l = wm * 64 + 16 * mi + lr;
            int nb = wn * 64 + 16 * nj + 4 * lg;
            uint2 pk;
            pk.x = pk2(acc[nj][mi][0] + bias[0], acc[nj][mi][1] + bias[1]);
            pk.y = pk2(acc[nj][mi][2] + bias[2], acc[nj][mi][3] + bias[3]);
            *(uint2*)((char*)C + ((tok_l * 256 + nb * 2) ^ ((tok_l & 7) << 4))) = pk;
        }
    }
    __syncthreads();
    const int sel = n0 >> 8;
    char* dstBase = ws + OFF_Q + (int64_t)sel * QKV_STRIDE;
    #pragma unroll
    for (int it = 0; it < 8; ++it) {
        int hh = it >> 1;
        int mrow = ((it & 1) << 6) | (t >> 2);
        int q4 = t & 3;
        uint4 v = *(const uint4*)((char*)C + ((mrow * 256 + hh * 64 + q4 * 16) ^ ((mrow & 7) << 4)));
        int m = m0 + mrow;
        int b = m / 49;
        int tok = m - b * 49;
        int h = ((n0 >> 5) + hh) & 7;
        *(uint4*)(dstBase + (((int64_t)b * 8 + h) * 49 + tok) * 64 + q4 * 16) = v;
    }
}

// ---------------------------------------------------------------------------
// attn: 1 block = 1 window, 8 waves = 8 heads. q/k fragments direct from ws;
// v staged to LDS as V^T [32 d][64 c] bf16 with tau baked into the column
// index (tok=16a+4g+ii -> c=32(a>>1)+8g+4(a&1)+ii) and XOR swizzle; plain
// ds_read_b128 then yields tau-ordered vf matching the in-lane pf pack.
// ---------------------------------------------------------------------------
__global__ __launch_bounds__(512, 2) void attn_kernel(char* __restrict__ ws) {
    __shared__ __align__(16) char smem[32768];   // VT [8 heads][4096]; OL [64][256] swz overlays
    const int b = blockIdx.x;
    const int t = threadIdx.x, l = t & 63, w = t >> 6;
    const int lr = l & 15, lg = l >> 4;
    const uint16_t* Q = (const uint16_t*)(ws + OFF_Q);
    const uint16_t* K = (const uint16_t*)(ws + OFF_K);
    const uint16_t* V = (const uint16_t*)(ws + OFF_V);
    const float*   rb = (const float*)(ws + OFF_RB);
    char* VL = smem + w * 4096;
    char* OL = smem;
    const float scale = 0.17677669529663687f * 1.4426950408889634f;
    const int64_t bh = (int64_t)b * 8 + w;

    // issue v global loads early (consumed after softmax: T14 split)
    uint4 vstage[4];
    int   vc[4];
    #pragma unroll
    for (int it = 0; it < 4; ++it) {
        int item = it * 64 + l;
        int tok = item >> 2, d0 = (item & 3) * 8;
        int a = tok >> 4, g = (tok >> 2) & 3, ii = tok & 3;
        vc[it] = (a >> 1) * 32 + g * 8 + (a & 1) * 4 + ii;
        uint4 v = {0u, 0u, 0u, 0u};
        if (tok < 49) v = *(const uint4*)(V + (bh * 49 + tok) * 32 + d0);
        vstage[it] = v;
    }

    // q/k fragments (plain layout, rows = tokens)
    bf16x8 qf[4], kf[4];
    #pragma unroll
    for (int nj = 0; nj < 4; ++nj)
        qf[nj] = *(const bf16x8*)(Q + (bh * 49 + 16 * nj + lr) * 32 + lg * 8);
    #pragma unroll
    for (int mj = 0; mj < 4; ++mj)
        kf[mj] = *(const bf16x8*)(K + (bh * 49 + 16 * mj + lr) * 32 + lg * 8);

    // S^T, softmax (exp2), tau-pack pf  (round-8 verified)
    float rs[4];
    bf16x8 pf[4][2];
    #pragma unroll
    for (int nj = 0; nj < 4; ++nj) {
        f32x4 s[4];
        __builtin_amdgcn_s_setprio(1);
        #pragma unroll
        for (int mj = 0; mj < 4; ++mj)
            s[mj] = __builtin_amdgcn_mfma_f32_16x16x32_bf16(
                kf[mj], qf[nj], (f32x4){0.f, 0.f, 0.f, 0.f}, 0, 0, 0);
        __builtin_amdgcn_s_setprio(0);
        #pragma unroll
        for (int mj = 0; mj < 4; ++mj) {
            f32x4 rbv = *(const f32x4*)(rb + ((w * 16 + 4 * mj + lg) * 64 + 16 * nj + lr) * 4);
            s[mj] = s[mj] * scale + rbv;
        }
        float m = s[0][0];
        #pragma unroll
        for (int mj = 0; mj < 4; ++mj)
            #pragma unroll
            for (int i = 0; i < 4; ++i) m = fmaxf(m, s[mj][i]);
        m = fmaxf(m, __shfl_xor(m, 16));
        m = fmaxf(m, __shfl_xor(m, 32));
        float sum = 0.f;
        #pragma unroll
        for (int mj = 0; mj < 4; ++mj)
            #pragma unroll
            for (int i = 0; i < 4; ++i) {
                float e = __builtin_amdgcn_exp2f(s[mj][i] - m);
                s[mj][i] = e;
                sum += e;
            }
        sum += __shfl_xor(sum, 16);
        sum += __shfl_xor(sum, 32);
        rs[nj] = sum;
        #pragma unroll
        for (int ks = 0; ks < 2; ++ks) {
            FragU f;
            f.u[0] = pk2(s[2 * ks][0], s[2 * ks][1]);
            f.u[1] = pk2(s[2 * ks][2], s[2 * ks][3]);
            f.u[2] = pk2(s[2 * ks + 1][0], s[2 * ks + 1][1]);
            f.u[3] = pk2(s[2 * ks + 1][2], s[2 * ks + 1][3]);
            pf[nj][ks] = f.v;
        }
    }

    // scatter staged v -> VT[d][c] (swz), wave-local
    #pragma unroll
    for (int it = 0; it < 4; ++it) {
        int item = it * 64 + l;
        int d0 = (item & 3) * 8;
        int c = vc[it];
        const uint32_t words[4] = {vstage[it].x, vstage[it].y, vstage[it].z, vstage[it].w};
        #pragma unroll
        for (int jj = 0; jj < 4; ++jj) {
            int dA = d0 + 2 * jj, dB = dA + 1;
            *(uint16_t*)(VL + ((dA * 128 + c * 2) ^ ((dA & 7) << 4))) = (uint16_t)words[jj];
            *(uint16_t*)(VL + ((dB * 128 + c * 2) ^ ((dB & 7) << 4))) = (uint16_t)(words[jj] >> 16);
        }
    }
    // vf fragments: plain swizzled b128 reads, tau-consistent with pf
    bf16x8 vf[2][2];
    #pragma unroll
    for (int dt = 0; dt < 2; ++dt)
        #pragma unroll
        for (int ks = 0; ks < 2; ++ks) {
            int row = dt * 16 + lr;
            vf[dt][ks] = *(const bf16x8*)(VL + ((row * 128 + ks * 64 + lg * 16) ^ ((row & 7) << 4)));
        }

    // PV: O^T = V^T · P^T
    f32x4 o[2][4];
    __builtin_amdgcn_s_setprio(1);
    #pragma unroll
    for (int dt = 0; dt < 2; ++dt)
        #pragma unroll
        for (int nj = 0; nj < 4; ++nj) {
            f32x4 acc = __builtin_amdgcn_mfma_f32_16x16x32_bf16(
                vf[dt][0], pf[nj][0], (f32x4){0.f, 0.f, 0.f, 0.f}, 0, 0, 0);
            o[dt][nj] = __builtin_amdgcn_mfma_f32_16x16x32_bf16(vf[dt][1], pf[nj][1], acc, 0, 0, 0);
        }
    __builtin_amdgcn_s_setprio(0);

    // all waves done with VT -> OL may overlay
    __syncthreads();
    #pragma unroll
    for (int nj = 0; nj < 4; ++nj) {
        const float rinv = 1.0f / rs[nj];
        const int row = 16 * nj + lr;
        const int swz = (row & 7) << 4;
        #pragma unroll
        for (int dt = 0; dt < 2; ++dt) {
            uint2 pk;
            pk.x = pk2(o[dt][nj][0] * rinv, o[dt][nj][1] * rinv);
            pk.y = pk2(o[dt][nj][2] * rinv, o[dt][nj][3] * rinv);
            *(uint2*)(OL + ((row * 512 + w * 64 + dt * 32 + lg * 8) ^ swz)) = pk;
        }
    }
    __syncthreads();
    // OL -> OWS [200704][256] bf16 (overlays V region, block-local rows)
    char* OWS = ws + OFF_V;
    #pragma unroll
    for (int it = 0; it < 4; ++it) {
        int c = it * 512 + t;
        if (c < 1568) {
            int tok = c >> 5, ch = c & 31;
            uint4 v = *(const uint4*)(OL + ((tok * 512 + ch * 16) ^ ((tok & 7) << 4)));
            *(uint4*)(OWS + ((int64_t)b * 49 + tok) * 512 + ch * 16) = v;
        }
    }
}

// ---------------------------------------------------------------------------
// proj GEMM: out[200704 x 256] = OWS[200704 x 256] @ wp^T + proj_b
// ---------------------------------------------------------------------------
__global__ __launch_bounds__(256, 2) void proj_kernel(const float* __restrict__ proj_b,
                                                      float* __restrict__ out,
                                                      const char* __restrict__ ws) {
    __shared__ __align__(16) char smem[65536];
    uint16_t* A  = (uint16_t*)smem;             // [128][64] swz
    uint16_t* Bt = (uint16_t*)(smem + 16384);   // [128][64] swz
    const uint16_t* OWS = (const uint16_t*)(ws + OFF_V);
    const uint16_t* wp  = (const uint16_t*)(ws + OFF_WP);
    const int m0 = blockIdx.x * 128, n0 = blockIdx.y * 128;
    const int t = threadIdx.x, l = t & 63, w = t >> 6;
    const int lr = l & 15, lg = l >> 4;
    const int wm = w >> 1, wn = w & 1;
    f32x4 acc[4][4];
    #pragma unroll
    for (int a = 0; a < 4; ++a)
        #pragma unroll
        for (int b2 = 0; b2 < 4; ++b2) acc[a][b2] = (f32x4){0.f, 0.f, 0.f, 0.f};

    for (int kk = 0; kk < 4; ++kk) {
        #pragma unroll
        for (int it = 0; it < 4; ++it) {
            int item = it * 256 + t;
            int r = item >> 3, ch = item & 7;
            uint4 va = *(const uint4*)(OWS + (int64_t)(m0 + r) * 256 + kk * 64 + ch * 8);
            *(uint4*)((char*)A + ((r * 128 + ch * 16) ^ ((r & 7) << 4))) = va;
            uint4 vb = *(const uint4*)(wp + (int64_t)(n0 + r) * 256 + kk * 64 + ch * 8);
            *(uint4*)((char*)Bt + ((r * 128 + ch * 16) ^ ((r & 7) << 4))) = vb;
        }
        __syncthreads();
        #pragma unroll
        for (int kh = 0; kh < 2; ++kh) {
            bf16x8 af[4], bfr[4];
            #pragma unroll
            for (int mi = 0; mi < 4; ++mi) {
                int r = wm * 64 + 16 * mi + lr;
                af[mi] = *(const bf16x8*)((char*)A + ((r * 128 + kh * 64 + lg * 16) ^ ((r & 7) << 4)));
            }
            #pragma unroll
            for (int nj = 0; nj < 4; ++nj) {
                int r = wn * 64 + 16 * nj + lr;
                bfr[nj] = *(const bf16x8*)((char*)Bt + ((r * 128 + kh * 64 + lg * 16) ^ ((r & 7) << 4)));
            }
            #pragma unroll
            for (int nj = 0; nj < 4; ++nj)
                #pragma unroll
                for (int mi = 0; mi < 4; ++mi)
                    acc[nj][mi] = __builtin_amdgcn_mfma_f32_16x16x32_bf16(bfr[nj], af[mi], acc[nj][mi], 0, 0, 0);
        }
        __syncthreads();
    }
    // epilogue: C_LDS [128 tok][128 n] fp32 (overlay), swz; bias in copy-out
    float* C = (float*)smem;
    #pragma unroll
    for (int nj = 0; nj < 4; ++nj)
        #pragma unroll
        for (int mi = 0; mi < 4; ++mi) {
            int tok_l = wm * 64 + 16 * mi + lr;
            int nb = wn * 64 + 16 * nj + 4 * lg;
            *(f32x4*)((char*)C + ((tok_l * 512 + nb * 4) ^ ((tok_l & 7) << 4))) = acc[nj][mi];
        }
    __syncthreads();
    #pragma unroll
    for (int it = 0; it < 16; ++it) {
        int c = it * 256 + t;
        int mrow = c >> 5, ch = c & 31;
        f32x4 v = *(const f32x4*)((char*)C + ((mrow * 512 + ch * 16) ^ ((mrow & 7) << 4)));
        f32x4 bias = *(const f32x4*)(proj_b + n0 + ch * 4);
        v = v + bias;
        *(f32x4*)(out + (int64_t)(m0 + mrow) * 256 + n0 + ch * 4) = v;
    }
}

extern "C" void kernel_launch(void* const* d_in, const int* in_sizes, int n_in,
                              void* d_out, int out_size, void* d_ws, size_t ws_size,
                              hipStream_t stream) {
    const float* x          = (const float*)d_in[0];
    const float* qkv_w      = (const float*)d_in[1];
    const float* qkv_b      = (const float*)d_in[2];
    const float* proj_w     = (const float*)d_in[3];
    const float* proj_b     = (const float*)d_in[4];
    const float* bias_table = (const float*)d_in[5];
    const int*   rel_index  = (const int*)d_in[6];
    float* out = (float*)d_out;
    char*  ws  = (char*)d_ws;

    prep_kernel<<<1155, 256, 0, stream>>>(qkv_w, proj_w, qkv_b, bias_table, rel_index, ws);
    qkv_kernel<<<dim3(1568, 6), 256, 0, stream>>>(x, ws);
    attn_kernel<<<NWIN, 512, 0, stream>>>(ws);
    proj_kernel<<<dim3(1568, 2), 256, 0, stream>>>(proj_b, out, ws);
}

// Round 11
// 376.382 us; speedup vs baseline: 1.0734x; 1.0734x over previous
//
#include <hip/hip_runtime.h>
#include <hip/hip_bf16.h>
#include <stdint.h>

#define NWIN 4096

typedef __attribute__((ext_vector_type(8))) short bf16x8;
typedef __attribute__((ext_vector_type(4))) float f32x4;

// ws layout (bytes):
//   wq  bf16 [768][256]  @0         (plain, row-major, = qkv_w cast)
//   wp  bf16 [256][256]  @393216
//   rb  f32  [8][16][64][4] @524288 ([h][kt>>2][qt][kt&3], *1/ln2, kt>=49 -> -1e30)
//   wsb f32  [768]       @655360    (qkv_b plain)
//   Q   bf16 [4096*8][49][32] @OFF_Q
//   K   bf16 ...          @OFF_K
//   V   bf16 ...          @OFF_V    (after attn, overwritten by OWS [200704][256] bf16)
#define OFF_WQ 0LL
#define OFF_WP 393216LL
#define OFF_RB 524288LL
#define OFF_B  655360LL
#define OFF_Q  1048576LL
#define QKV_STRIDE 102760448LL
#define OFF_K  (OFF_Q + QKV_STRIDE)
#define OFF_V  (OFF_Q + 2 * QKV_STRIDE)

static __device__ __forceinline__ uint32_t f2bf(float f) {
    union { float f; uint32_t u; } v; v.f = f;
    return (v.u + 0x7FFFu + ((v.u >> 16) & 1u)) >> 16;
}

static __device__ __forceinline__ uint32_t pk2(float lo, float hi) {
    union { __hip_bfloat162 h; uint32_t u; } c;
    c.h = __float22bfloat162_rn(float2{lo, hi});
    return c.u;
}

union FragU { uint32_t u[4]; bf16x8 v; };

// ---------------------------------------------------------------------------
// prep: weights fp32->bf16 (plain), rb gather (*1/ln2, kt>=49 -> -1e30), bias
// ---------------------------------------------------------------------------
__global__ void prep_kernel(const float* __restrict__ qkv_w, const float* __restrict__ proj_w,
                            const float* __restrict__ qkv_b,
                            const float* __restrict__ bias_table, const int* __restrict__ rel_index,
                            char* __restrict__ ws) {
    uint16_t* wq  = (uint16_t*)(ws + OFF_WQ);
    uint16_t* wp  = (uint16_t*)(ws + OFF_WP);
    float*    rb  = (float*)(ws + OFF_RB);
    float*    wsb = (float*)(ws + OFF_B);
    const int total = 196608 + 65536 + 32768 + 768;
    for (int idx = blockIdx.x * blockDim.x + threadIdx.x; idx < total;
         idx += gridDim.x * blockDim.x) {
        if (idx < 196608) {
            wq[idx] = (uint16_t)f2bf(qkv_w[idx]);
        } else if (idx < 262144) {
            int i = idx - 196608;
            wp[i] = (uint16_t)f2bf(proj_w[i]);
        } else if (idx < 294912) {
            int i = idx - 262144;                 // [h][kt4][qt][ii]
            int h = i >> 12, kt4 = (i >> 8) & 15, qt = (i >> 2) & 63, ii = i & 3;
            int kt = kt4 * 4 + ii;
            float v = -1e30f;
            if (kt < 49 && qt < 49)
                v = bias_table[rel_index[qt * 49 + kt] * 8 + h] * 1.4426950408889634f;
            rb[i] = v;
        } else {
            int n = idx - 294912;
            wsb[n] = qkv_b[n];
        }
    }
}

// ---------------------------------------------------------------------------
// qkv GEMM: [200704 x 768] = x[200704 x 256] @ wq^T, 128x128 tiles, BK=64.
// Grid (6, 1568): n-block fastest -> the 6 blocks sharing an m-tile run
// adjacently and hit the same x tile in L2/L3 (x streamed from HBM once).
// ---------------------------------------------------------------------------
__global__ __launch_bounds__(256, 2) void qkv_kernel(const float* __restrict__ x,
                                                     char* __restrict__ ws) {
    __shared__ __align__(16) char smem[32768];
    uint16_t* A  = (uint16_t*)smem;             // [128][64] swz
    uint16_t* Bt = (uint16_t*)(smem + 16384);   // [128][64] swz
    const uint16_t* wq  = (const uint16_t*)(ws + OFF_WQ);
    const float*    wsb = (const float*)(ws + OFF_B);
    const int m0 = blockIdx.y * 128, n0 = blockIdx.x * 128;
    const int t = threadIdx.x, l = t & 63, w = t >> 6;
    const int lr = l & 15, lg = l >> 4;
    const int wm = w >> 1, wn = w & 1;
    f32x4 acc[4][4];
    #pragma unroll
    for (int a = 0; a < 4; ++a)
        #pragma unroll
        for (int b2 = 0; b2 < 4; ++b2) acc[a][b2] = (f32x4){0.f, 0.f, 0.f, 0.f};

    for (int kk = 0; kk < 4; ++kk) {
        #pragma unroll
        for (int it = 0; it < 4; ++it) {                 // A: x fp32 -> bf16, swz
            int item = it * 256 + t;
            int r = item >> 3, ch = item & 7;
            const float* src = x + (int64_t)(m0 + r) * 256 + kk * 64 + ch * 8;
            float4 v0 = *(const float4*)src;
            float4 v1 = *(const float4*)(src + 4);
            uint4 pk;
            pk.x = pk2(v0.x, v0.y); pk.y = pk2(v0.z, v0.w);
            pk.z = pk2(v1.x, v1.y); pk.w = pk2(v1.z, v1.w);
            *(uint4*)((char*)A + ((r * 128 + ch * 16) ^ ((r & 7) << 4))) = pk;
        }
        #pragma unroll
        for (int it = 0; it < 4; ++it) {                 // B: wq bf16, swz
            int item = it * 256 + t;
            int r = item >> 3, ch = item & 7;
            uint4 v = *(const uint4*)(wq + (int64_t)(n0 + r) * 256 + kk * 64 + ch * 8);
            *(uint4*)((char*)Bt + ((r * 128 + ch * 16) ^ ((r & 7) << 4))) = v;
        }
        __syncthreads();
        #pragma unroll
        for (int kh = 0; kh < 2; ++kh) {
            bf16x8 af[4], bfr[4];
            #pragma unroll
            for (int mi = 0; mi < 4; ++mi) {
                int r = wm * 64 + 16 * mi + lr;
                af[mi] = *(const bf16x8*)((char*)A + ((r * 128 + kh * 64 + lg * 16) ^ ((r & 7) << 4)));
            }
            #pragma unroll
            for (int nj = 0; nj < 4; ++nj) {
                int r = wn * 64 + 16 * nj + lr;
                bfr[nj] = *(const bf16x8*)((char*)Bt + ((r * 128 + kh * 64 + lg * 16) ^ ((r & 7) << 4)));
            }
            #pragma unroll
            for (int nj = 0; nj < 4; ++nj)
                #pragma unroll
                for (int mi = 0; mi < 4; ++mi)
                    acc[nj][mi] = __builtin_amdgcn_mfma_f32_16x16x32_bf16(bfr[nj], af[mi], acc[nj][mi], 0, 0, 0);
        }
        __syncthreads();
    }
    // epilogue: bias + C_LDS [128 tok][128 n] bf16 (overlay A/B), swz by tok
    uint16_t* C = (uint16_t*)smem;
    #pragma unroll
    for (int nj = 0; nj < 4; ++nj) {
        f32x4 bias = *(const f32x4*)(wsb + n0 + wn * 64 + 16 * nj + 4 * lg);
        #pragma unroll
        for (int mi = 0; mi < 4; ++mi) {
            int tok_l = wm * 64 + 16 * mi + lr;
            int nb = wn * 64 + 16 * nj + 4 * lg;
            uint2 pk;
            pk.x = pk2(acc[nj][mi][0] + bias[0], acc[nj][mi][1] + bias[1]);
            pk.y = pk2(acc[nj][mi][2] + bias[2], acc[nj][mi][3] + bias[3]);
            *(uint2*)((char*)C + ((tok_l * 256 + nb * 2) ^ ((tok_l & 7) << 4))) = pk;
        }
    }
    __syncthreads();
    const int sel = n0 >> 8;
    char* dstBase = ws + OFF_Q + (int64_t)sel * QKV_STRIDE;
    #pragma unroll
    for (int it = 0; it < 8; ++it) {
        int hh = it >> 1;
        int mrow = ((it & 1) << 6) | (t >> 2);
        int q4 = t & 3;
        uint4 v = *(const uint4*)((char*)C + ((mrow * 256 + hh * 64 + q4 * 16) ^ ((mrow & 7) << 4)));
        int m = m0 + mrow;
        int b = m / 49;
        int tok = m - b * 49;
        int h = ((n0 >> 5) + hh) & 7;
        *(uint4*)(dstBase + (((int64_t)b * 8 + h) * 49 + tok) * 64 + q4 * 16) = v;
    }
}

// ---------------------------------------------------------------------------
// attn: 1 block = 1 window, 8 waves = 8 heads. q/k fragments direct from ws;
// v staged to LDS as V^T [32 d][64 c] bf16 with tau baked into the column
// index (tok=16a+4g+ii -> c=32(a>>1)+8g+4(a&1)+ii) and XOR swizzle; plain
// ds_read_b128 then yields tau-ordered vf matching the in-lane pf pack.
// ---------------------------------------------------------------------------
__global__ __launch_bounds__(512, 2) void attn_kernel(char* __restrict__ ws) {
    __shared__ __align__(16) char smem[32768];   // VT [8 heads][4096]; OL [64][256] swz overlays
    const int b = blockIdx.x;
    const int t = threadIdx.x, l = t & 63, w = t >> 6;
    const int lr = l & 15, lg = l >> 4;
    const uint16_t* Q = (const uint16_t*)(ws + OFF_Q);
    const uint16_t* K = (const uint16_t*)(ws + OFF_K);
    const uint16_t* V = (const uint16_t*)(ws + OFF_V);
    const float*   rb = (const float*)(ws + OFF_RB);
    char* VL = smem + w * 4096;
    char* OL = smem;
    const float scale = 0.17677669529663687f * 1.4426950408889634f;
    const int64_t bh = (int64_t)b * 8 + w;

    // issue v global loads early (consumed after softmax: T14 split)
    uint4 vstage[4];
    int   vc[4];
    #pragma unroll
    for (int it = 0; it < 4; ++it) {
        int item = it * 64 + l;
        int tok = item >> 2, d0 = (item & 3) * 8;
        int a = tok >> 4, g = (tok >> 2) & 3, ii = tok & 3;
        vc[it] = (a >> 1) * 32 + g * 8 + (a & 1) * 4 + ii;
        uint4 v = {0u, 0u, 0u, 0u};
        if (tok < 49) v = *(const uint4*)(V + (bh * 49 + tok) * 32 + d0);
        vstage[it] = v;
    }

    // q/k fragments (plain layout, rows = tokens)
    bf16x8 qf[4], kf[4];
    #pragma unroll
    for (int nj = 0; nj < 4; ++nj)
        qf[nj] = *(const bf16x8*)(Q + (bh * 49 + 16 * nj + lr) * 32 + lg * 8);
    #pragma unroll
    for (int mj = 0; mj < 4; ++mj)
        kf[mj] = *(const bf16x8*)(K + (bh * 49 + 16 * mj + lr) * 32 + lg * 8);

    // S^T, softmax (exp2), tau-pack pf  (round-8 verified)
    float rs[4];
    bf16x8 pf[4][2];
    #pragma unroll
    for (int nj = 0; nj < 4; ++nj) {
        f32x4 s[4];
        __builtin_amdgcn_s_setprio(1);
        #pragma unroll
        for (int mj = 0; mj < 4; ++mj)
            s[mj] = __builtin_amdgcn_mfma_f32_16x16x32_bf16(
                kf[mj], qf[nj], (f32x4){0.f, 0.f, 0.f, 0.f}, 0, 0, 0);
        __builtin_amdgcn_s_setprio(0);
        #pragma unroll
        for (int mj = 0; mj < 4; ++mj) {
            f32x4 rbv = *(const f32x4*)(rb + ((w * 16 + 4 * mj + lg) * 64 + 16 * nj + lr) * 4);
            s[mj] = s[mj] * scale + rbv;
        }
        float m = s[0][0];
        #pragma unroll
        for (int mj = 0; mj < 4; ++mj)
            #pragma unroll
            for (int i = 0; i < 4; ++i) m = fmaxf(m, s[mj][i]);
        m = fmaxf(m, __shfl_xor(m, 16));
        m = fmaxf(m, __shfl_xor(m, 32));
        float sum = 0.f;
        #pragma unroll
        for (int mj = 0; mj < 4; ++mj)
            #pragma unroll
            for (int i = 0; i < 4; ++i) {
                float e = __builtin_amdgcn_exp2f(s[mj][i] - m);
                s[mj][i] = e;
                sum += e;
            }
        sum += __shfl_xor(sum, 16);
        sum += __shfl_xor(sum, 32);
        rs[nj] = sum;
        #pragma unroll
        for (int ks = 0; ks < 2; ++ks) {
            FragU f;
            f.u[0] = pk2(s[2 * ks][0], s[2 * ks][1]);
            f.u[1] = pk2(s[2 * ks][2], s[2 * ks][3]);
            f.u[2] = pk2(s[2 * ks + 1][0], s[2 * ks + 1][1]);
            f.u[3] = pk2(s[2 * ks + 1][2], s[2 * ks + 1][3]);
            pf[nj][ks] = f.v;
        }
    }

    // scatter staged v -> VT[d][c] (swz), wave-local
    #pragma unroll
    for (int it = 0; it < 4; ++it) {
        int item = it * 64 + l;
        int d0 = (item & 3) * 8;
        int c = vc[it];
        const uint32_t words[4] = {vstage[it].x, vstage[it].y, vstage[it].z, vstage[it].w};
        #pragma unroll
        for (int jj = 0; jj < 4; ++jj) {
            int dA = d0 + 2 * jj, dB = dA + 1;
            *(uint16_t*)(VL + ((dA * 128 + c * 2) ^ ((dA & 7) << 4))) = (uint16_t)words[jj];
            *(uint16_t*)(VL + ((dB * 128 + c * 2) ^ ((dB & 7) << 4))) = (uint16_t)(words[jj] >> 16);
        }
    }
    // vf fragments: plain swizzled b128 reads, tau-consistent with pf
    bf16x8 vf[2][2];
    #pragma unroll
    for (int dt = 0; dt < 2; ++dt)
        #pragma unroll
        for (int ks = 0; ks < 2; ++ks) {
            int row = dt * 16 + lr;
            vf[dt][ks] = *(const bf16x8*)(VL + ((row * 128 + ks * 64 + lg * 16) ^ ((row & 7) << 4)));
        }

    // PV: O^T = V^T · P^T
    f32x4 o[2][4];
    __builtin_amdgcn_s_setprio(1);
    #pragma unroll
    for (int dt = 0; dt < 2; ++dt)
        #pragma unroll
        for (int nj = 0; nj < 4; ++nj) {
            f32x4 acc = __builtin_amdgcn_mfma_f32_16x16x32_bf16(
                vf[dt][0], pf[nj][0], (f32x4){0.f, 0.f, 0.f, 0.f}, 0, 0, 0);
            o[dt][nj] = __builtin_amdgcn_mfma_f32_16x16x32_bf16(vf[dt][1], pf[nj][1], acc, 0, 0, 0);
        }
    __builtin_amdgcn_s_setprio(0);

    // all waves done with VT -> OL may overlay
    __syncthreads();
    #pragma unroll
    for (int nj = 0; nj < 4; ++nj) {
        const float rinv = 1.0f / rs[nj];
        const int row = 16 * nj + lr;
        const int swz = (row & 7) << 4;
        #pragma unroll
        for (int dt = 0; dt < 2; ++dt) {
            uint2 pk;
            pk.x = pk2(o[dt][nj][0] * rinv, o[dt][nj][1] * rinv);
            pk.y = pk2(o[dt][nj][2] * rinv, o[dt][nj][3] * rinv);
            *(uint2*)(OL + ((row * 512 + w * 64 + dt * 32 + lg * 8) ^ swz)) = pk;
        }
    }
    __syncthreads();
    // OL -> OWS [200704][256] bf16 (overlays V region, block-local rows)
    char* OWS = ws + OFF_V;
    #pragma unroll
    for (int it = 0; it < 4; ++it) {
        int c = it * 512 + t;
        if (c < 1568) {
            int tok = c >> 5, ch = c & 31;
            uint4 v = *(const uint4*)(OL + ((tok * 512 + ch * 16) ^ ((tok & 7) << 4)));
            *(uint4*)(OWS + ((int64_t)b * 49 + tok) * 512 + ch * 16) = v;
        }
    }
}

// ---------------------------------------------------------------------------
// proj GEMM: out[200704 x 256] = OWS[200704 x 256] @ wp^T + proj_b
// ---------------------------------------------------------------------------
__global__ __launch_bounds__(256, 2) void proj_kernel(const float* __restrict__ proj_b,
                                                      float* __restrict__ out,
                                                      const char* __restrict__ ws) {
    __shared__ __align__(16) char smem[65536];
    uint16_t* A  = (uint16_t*)smem;             // [128][64] swz
    uint16_t* Bt = (uint16_t*)(smem + 16384);   // [128][64] swz
    const uint16_t* OWS = (const uint16_t*)(ws + OFF_V);
    const uint16_t* wp  = (const uint16_t*)(ws + OFF_WP);
    const int m0 = blockIdx.y * 128, n0 = blockIdx.x * 128;
    const int t = threadIdx.x, l = t & 63, w = t >> 6;
    const int lr = l & 15, lg = l >> 4;
    const int wm = w >> 1, wn = w & 1;
    f32x4 acc[4][4];
    #pragma unroll
    for (int a = 0; a < 4; ++a)
        #pragma unroll
        for (int b2 = 0; b2 < 4; ++b2) acc[a][b2] = (f32x4){0.f, 0.f, 0.f, 0.f};

    for (int kk = 0; kk < 4; ++kk) {
        #pragma unroll
        for (int it = 0; it < 4; ++it) {
            int item = it * 256 + t;
            int r = item >> 3, ch = item & 7;
            uint4 va = *(const uint4*)(OWS + (int64_t)(m0 + r) * 256 + kk * 64 + ch * 8);
            *(uint4*)((char*)A + ((r * 128 + ch * 16) ^ ((r & 7) << 4))) = va;
            uint4 vb = *(const uint4*)(wp + (int64_t)(n0 + r) * 256 + kk * 64 + ch * 8);
            *(uint4*)((char*)Bt + ((r * 128 + ch * 16) ^ ((r & 7) << 4))) = vb;
        }
        __syncthreads();
        #pragma unroll
        for (int kh = 0; kh < 2; ++kh) {
            bf16x8 af[4], bfr[4];
            #pragma unroll
            for (int mi = 0; mi < 4; ++mi) {
                int r = wm * 64 + 16 * mi + lr;
                af[mi] = *(const bf16x8*)((char*)A + ((r * 128 + kh * 64 + lg * 16) ^ ((r & 7) << 4)));
            }
            #pragma unroll
            for (int nj = 0; nj < 4; ++nj) {
                int r = wn * 64 + 16 * nj + lr;
                bfr[nj] = *(const bf16x8*)((char*)Bt + ((r * 128 + kh * 64 + lg * 16) ^ ((r & 7) << 4)));
            }
            #pragma unroll
            for (int nj = 0; nj < 4; ++nj)
                #pragma unroll
                for (int mi = 0; mi < 4; ++mi)
                    acc[nj][mi] = __builtin_amdgcn_mfma_f32_16x16x32_bf16(bfr[nj], af[mi], acc[nj][mi], 0, 0, 0);
        }
        __syncthreads();
    }
    // epilogue: C_LDS [128 tok][128 n] fp32 (overlay), swz; bias in copy-out
    float* C = (float*)smem;
    #pragma unroll
    for (int nj = 0; nj < 4; ++nj)
        #pragma unroll
        for (int mi = 0; mi < 4; ++mi) {
            int tok_l = wm * 64 + 16 * mi + lr;
            int nb = wn * 64 + 16 * nj + 4 * lg;
            *(f32x4*)((char*)C + ((tok_l * 512 + nb * 4) ^ ((tok_l & 7) << 4))) = acc[nj][mi];
        }
    __syncthreads();
    #pragma unroll
    for (int it = 0; it < 16; ++it) {
        int c = it * 256 + t;
        int mrow = c >> 5, ch = c & 31;
        f32x4 v = *(const f32x4*)((char*)C + ((mrow * 512 + ch * 16) ^ ((mrow & 7) << 4)));
        f32x4 bias = *(const f32x4*)(proj_b + n0 + ch * 4);
        v = v + bias;
        *(f32x4*)(out + (int64_t)(m0 + mrow) * 256 + n0 + ch * 4) = v;
    }
}

extern "C" void kernel_launch(void* const* d_in, const int* in_sizes, int n_in,
                              void* d_out, int out_size, void* d_ws, size_t ws_size,
                              hipStream_t stream) {
    const float* x          = (const float*)d_in[0];
    const float* qkv_w      = (const float*)d_in[1];
    const float* qkv_b      = (const float*)d_in[2];
    const float* proj_w     = (const float*)d_in[3];
    const float* proj_b     = (const float*)d_in[4];
    const float* bias_table = (const float*)d_in[5];
    const int*   rel_index  = (const int*)d_in[6];
    float* out = (float*)d_out;
    char*  ws  = (char*)d_ws;

    prep_kernel<<<1155, 256, 0, stream>>>(qkv_w, proj_w, qkv_b, bias_table, rel_index, ws);
    qkv_kernel<<<dim3(6, 1568), 256, 0, stream>>>(x, ws);
    attn_kernel<<<NWIN, 512, 0, stream>>>(ws);
    proj_kernel<<<dim3(2, 1568), 256, 0, stream>>>(proj_b, out, ws);
}

// Round 12
// 327.745 us; speedup vs baseline: 1.2327x; 1.1484x over previous
//
#include <hip/hip_runtime.h>
#include <hip/hip_bf16.h>
#include <stdint.h>

#define NWIN 4096

typedef __attribute__((ext_vector_type(8))) short bf16x8;
typedef __attribute__((ext_vector_type(4))) float f32x4;

// ws layout (bytes):
//   wq  bf16 [768][256]  @0         (plain, row-major, = qkv_w cast)
//   wp  bf16 [256][256]  @393216
//   rb  f32  [8][16][64][4] @524288 ([h][kt>>2][qt][kt&3], *1/ln2, kt>=49 -> -1e30)
//   wsb f32  [768]       @655360    (qkv_b plain)
//   Q   bf16 [4096*8][49][32] @OFF_Q
//   K   bf16 ...          @OFF_K
//   V   bf16 ...          @OFF_V    (after attn, overwritten by OWS [200704][256] bf16)
#define OFF_WQ 0LL
#define OFF_WP 393216LL
#define OFF_RB 524288LL
#define OFF_B  655360LL
#define OFF_Q  1048576LL
#define QKV_STRIDE 102760448LL
#define OFF_K  (OFF_Q + QKV_STRIDE)
#define OFF_V  (OFF_Q + 2 * QKV_STRIDE)

static __device__ __forceinline__ uint32_t f2bf(float f) {
    union { float f; uint32_t u; } v; v.f = f;
    return (v.u + 0x7FFFu + ((v.u >> 16) & 1u)) >> 16;
}

static __device__ __forceinline__ uint32_t pk2(float lo, float hi) {
    union { __hip_bfloat162 h; uint32_t u; } c;
    c.h = __float22bfloat162_rn(float2{lo, hi});
    return c.u;
}

union FragU { uint32_t u[4]; bf16x8 v; };

// ---------------------------------------------------------------------------
// prep: weights fp32->bf16 (plain), rb gather (*1/ln2, kt>=49 -> -1e30), bias
// ---------------------------------------------------------------------------
__global__ void prep_kernel(const float* __restrict__ qkv_w, const float* __restrict__ proj_w,
                            const float* __restrict__ qkv_b,
                            const float* __restrict__ bias_table, const int* __restrict__ rel_index,
                            char* __restrict__ ws) {
    uint16_t* wq  = (uint16_t*)(ws + OFF_WQ);
    uint16_t* wp  = (uint16_t*)(ws + OFF_WP);
    float*    rb  = (float*)(ws + OFF_RB);
    float*    wsb = (float*)(ws + OFF_B);
    const int total = 196608 + 65536 + 32768 + 768;
    for (int idx = blockIdx.x * blockDim.x + threadIdx.x; idx < total;
         idx += gridDim.x * blockDim.x) {
        if (idx < 196608) {
            wq[idx] = (uint16_t)f2bf(qkv_w[idx]);
        } else if (idx < 262144) {
            int i = idx - 196608;
            wp[i] = (uint16_t)f2bf(proj_w[i]);
        } else if (idx < 294912) {
            int i = idx - 262144;                 // [h][kt4][qt][ii]
            int h = i >> 12, kt4 = (i >> 8) & 15, qt = (i >> 2) & 63, ii = i & 3;
            int kt = kt4 * 4 + ii;
            float v = -1e30f;
            if (kt < 49 && qt < 49)
                v = bias_table[rel_index[qt * 49 + kt] * 8 + h] * 1.4426950408889634f;
            rb[i] = v;
        } else {
            int n = idx - 294912;
            wsb[n] = qkv_b[n];
        }
    }
}

// ---------------------------------------------------------------------------
// qkv GEMM: [200704 x 768] = x[200704 x 256] @ wq^T, 128x128 tiles, BK=64.
// XCD-aware supertile dispatch: p = s*48 + j*8 + gm  (48%8==0) ->
// all 6 n-blocks of m-tile g = s*8+gm land on the SAME XCD, adjacently.
// x tile is fetched into that XCD's L2 once.
// ---------------------------------------------------------------------------
__global__ __launch_bounds__(256, 2) void qkv_kernel(const float* __restrict__ x,
                                                     char* __restrict__ ws) {
    __shared__ __align__(16) char smem[32768];
    uint16_t* A  = (uint16_t*)smem;             // [128][64] swz
    uint16_t* Bt = (uint16_t*)(smem + 16384);   // [128][64] swz
    const uint16_t* wq  = (const uint16_t*)(ws + OFF_WQ);
    const float*    wsb = (const float*)(ws + OFF_B);
    const int P = blockIdx.x;
    const int s = P / 48, r = P % 48;
    const int g = s * 8 + (r & 7);              // m-tile 0..1567
    const int m0 = g * 128, n0 = (r >> 3) * 128;
    const int t = threadIdx.x, l = t & 63, w = t >> 6;
    const int lr = l & 15, lg = l >> 4;
    const int wm = w >> 1, wn = w & 1;
    f32x4 acc[4][4];
    #pragma unroll
    for (int a = 0; a < 4; ++a)
        #pragma unroll
        for (int b2 = 0; b2 < 4; ++b2) acc[a][b2] = (f32x4){0.f, 0.f, 0.f, 0.f};

    for (int kk = 0; kk < 4; ++kk) {
        #pragma unroll
        for (int it = 0; it < 4; ++it) {                 // A: x fp32 -> bf16, swz
            int item = it * 256 + t;
            int rr = item >> 3, ch = item & 7;
            const float* src = x + (int64_t)(m0 + rr) * 256 + kk * 64 + ch * 8;
            float4 v0 = *(const float4*)src;
            float4 v1 = *(const float4*)(src + 4);
            uint4 pk;
            pk.x = pk2(v0.x, v0.y); pk.y = pk2(v0.z, v0.w);
            pk.z = pk2(v1.x, v1.y); pk.w = pk2(v1.z, v1.w);
            *(uint4*)((char*)A + ((rr * 128 + ch * 16) ^ ((rr & 7) << 4))) = pk;
        }
        #pragma unroll
        for (int it = 0; it < 4; ++it) {                 // B: wq bf16, swz
            int item = it * 256 + t;
            int rr = item >> 3, ch = item & 7;
            uint4 v = *(const uint4*)(wq + (int64_t)(n0 + rr) * 256 + kk * 64 + ch * 8);
            *(uint4*)((char*)Bt + ((rr * 128 + ch * 16) ^ ((rr & 7) << 4))) = v;
        }
        __syncthreads();
        #pragma unroll
        for (int kh = 0; kh < 2; ++kh) {
            bf16x8 af[4], bfr[4];
            #pragma unroll
            for (int mi = 0; mi < 4; ++mi) {
                int rr = wm * 64 + 16 * mi + lr;
                af[mi] = *(const bf16x8*)((char*)A + ((rr * 128 + kh * 64 + lg * 16) ^ ((rr & 7) << 4)));
            }
            #pragma unroll
            for (int nj = 0; nj < 4; ++nj) {
                int rr = wn * 64 + 16 * nj + lr;
                bfr[nj] = *(const bf16x8*)((char*)Bt + ((rr * 128 + kh * 64 + lg * 16) ^ ((rr & 7) << 4)));
            }
            #pragma unroll
            for (int nj = 0; nj < 4; ++nj)
                #pragma unroll
                for (int mi = 0; mi < 4; ++mi)
                    acc[nj][mi] = __builtin_amdgcn_mfma_f32_16x16x32_bf16(bfr[nj], af[mi], acc[nj][mi], 0, 0, 0);
        }
        __syncthreads();
    }
    // epilogue: bias + C_LDS [128 tok][128 n] bf16 (overlay A/B), swz by tok
    uint16_t* C = (uint16_t*)smem;
    #pragma unroll
    for (int nj = 0; nj < 4; ++nj) {
        f32x4 bias = *(const f32x4*)(wsb + n0 + wn * 64 + 16 * nj + 4 * lg);
        #pragma unroll
        for (int mi = 0; mi < 4; ++mi) {
            int tok_l = wm * 64 + 16 * mi + lr;
            int nb = wn * 64 + 16 * nj + 4 * lg;
            uint2 pk;
            pk.x = pk2(acc[nj][mi][0] + bias[0], acc[nj][mi][1] + bias[1]);
            pk.y = pk2(acc[nj][mi][2] + bias[2], acc[nj][mi][3] + bias[3]);
            *(uint2*)((char*)C + ((tok_l * 256 + nb * 2) ^ ((tok_l & 7) << 4))) = pk;
        }
    }
    __syncthreads();
    const int sel = n0 >> 8;
    char* dstBase = ws + OFF_Q + (int64_t)sel * QKV_STRIDE;
    #pragma unroll
    for (int it = 0; it < 8; ++it) {
        int hh = it >> 1;
        int mrow = ((it & 1) << 6) | (t >> 2);
        int q4 = t & 3;
        uint4 v = *(const uint4*)((char*)C + ((mrow * 256 + hh * 64 + q4 * 16) ^ ((mrow & 7) << 4)));
        int m = m0 + mrow;
        int b = m / 49;
        int tok = m - b * 49;
        int h = ((n0 >> 5) + hh) & 7;
        *(uint4*)(dstBase + (((int64_t)b * 8 + h) * 49 + tok) * 64 + q4 * 16) = v;
    }
}

// ---------------------------------------------------------------------------
// attn: 1 block = 1 window, 8 waves = 8 heads. q/k fragments direct from ws;
// v staged to LDS as V^T [32 d][64 c] bf16 with tau baked into the column
// index (tok=16a+4g+ii -> c=32(a>>1)+8g+4(a&1)+ii) and XOR swizzle; plain
// ds_read_b128 then yields tau-ordered vf matching the in-lane pf pack.
// ---------------------------------------------------------------------------
__global__ __launch_bounds__(512, 2) void attn_kernel(char* __restrict__ ws) {
    __shared__ __align__(16) char smem[32768];   // VT [8 heads][4096]; OL [64][256] swz overlays
    const int b = blockIdx.x;
    const int t = threadIdx.x, l = t & 63, w = t >> 6;
    const int lr = l & 15, lg = l >> 4;
    const uint16_t* Q = (const uint16_t*)(ws + OFF_Q);
    const uint16_t* K = (const uint16_t*)(ws + OFF_K);
    const uint16_t* V = (const uint16_t*)(ws + OFF_V);
    const float*   rb = (const float*)(ws + OFF_RB);
    char* VL = smem + w * 4096;
    char* OL = smem;
    const float scale = 0.17677669529663687f * 1.4426950408889634f;
    const int64_t bh = (int64_t)b * 8 + w;

    // issue v global loads early (consumed after softmax: T14 split)
    uint4 vstage[4];
    int   vc[4];
    #pragma unroll
    for (int it = 0; it < 4; ++it) {
        int item = it * 64 + l;
        int tok = item >> 2, d0 = (item & 3) * 8;
        int a = tok >> 4, g = (tok >> 2) & 3, ii = tok & 3;
        vc[it] = (a >> 1) * 32 + g * 8 + (a & 1) * 4 + ii;
        uint4 v = {0u, 0u, 0u, 0u};
        if (tok < 49) v = *(const uint4*)(V + (bh * 49 + tok) * 32 + d0);
        vstage[it] = v;
    }

    // q/k fragments (plain layout, rows = tokens)
    bf16x8 qf[4], kf[4];
    #pragma unroll
    for (int nj = 0; nj < 4; ++nj)
        qf[nj] = *(const bf16x8*)(Q + (bh * 49 + 16 * nj + lr) * 32 + lg * 8);
    #pragma unroll
    for (int mj = 0; mj < 4; ++mj)
        kf[mj] = *(const bf16x8*)(K + (bh * 49 + 16 * mj + lr) * 32 + lg * 8);

    // S^T, softmax (exp2), tau-pack pf  (round-8 verified)
    float rs[4];
    bf16x8 pf[4][2];
    #pragma unroll
    for (int nj = 0; nj < 4; ++nj) {
        f32x4 s[4];
        __builtin_amdgcn_s_setprio(1);
        #pragma unroll
        for (int mj = 0; mj < 4; ++mj)
            s[mj] = __builtin_amdgcn_mfma_f32_16x16x32_bf16(
                kf[mj], qf[nj], (f32x4){0.f, 0.f, 0.f, 0.f}, 0, 0, 0);
        __builtin_amdgcn_s_setprio(0);
        #pragma unroll
        for (int mj = 0; mj < 4; ++mj) {
            f32x4 rbv = *(const f32x4*)(rb + ((w * 16 + 4 * mj + lg) * 64 + 16 * nj + lr) * 4);
            s[mj] = s[mj] * scale + rbv;
        }
        float m = s[0][0];
        #pragma unroll
        for (int mj = 0; mj < 4; ++mj)
            #pragma unroll
            for (int i = 0; i < 4; ++i) m = fmaxf(m, s[mj][i]);
        m = fmaxf(m, __shfl_xor(m, 16));
        m = fmaxf(m, __shfl_xor(m, 32));
        float sum = 0.f;
        #pragma unroll
        for (int mj = 0; mj < 4; ++mj)
            #pragma unroll
            for (int i = 0; i < 4; ++i) {
                float e = __builtin_amdgcn_exp2f(s[mj][i] - m);
                s[mj][i] = e;
                sum += e;
            }
        sum += __shfl_xor(sum, 16);
        sum += __shfl_xor(sum, 32);
        rs[nj] = sum;
        #pragma unroll
        for (int ks = 0; ks < 2; ++ks) {
            FragU f;
            f.u[0] = pk2(s[2 * ks][0], s[2 * ks][1]);
            f.u[1] = pk2(s[2 * ks][2], s[2 * ks][3]);
            f.u[2] = pk2(s[2 * ks + 1][0], s[2 * ks + 1][1]);
            f.u[3] = pk2(s[2 * ks + 1][2], s[2 * ks + 1][3]);
            pf[nj][ks] = f.v;
        }
    }

    // scatter staged v -> VT[d][c] (swz), wave-local
    #pragma unroll
    for (int it = 0; it < 4; ++it) {
        int item = it * 64 + l;
        int d0 = (item & 3) * 8;
        int c = vc[it];
        const uint32_t words[4] = {vstage[it].x, vstage[it].y, vstage[it].z, vstage[it].w};
        #pragma unroll
        for (int jj = 0; jj < 4; ++jj) {
            int dA = d0 + 2 * jj, dB = dA + 1;
            *(uint16_t*)(VL + ((dA * 128 + c * 2) ^ ((dA & 7) << 4))) = (uint16_t)words[jj];
            *(uint16_t*)(VL + ((dB * 128 + c * 2) ^ ((dB & 7) << 4))) = (uint16_t)(words[jj] >> 16);
        }
    }
    // vf fragments: plain swizzled b128 reads, tau-consistent with pf
    bf16x8 vf[2][2];
    #pragma unroll
    for (int dt = 0; dt < 2; ++dt)
        #pragma unroll
        for (int ks = 0; ks < 2; ++ks) {
            int row = dt * 16 + lr;
            vf[dt][ks] = *(const bf16x8*)(VL + ((row * 128 + ks * 64 + lg * 16) ^ ((row & 7) << 4)));
        }

    // PV: O^T = V^T · P^T
    f32x4 o[2][4];
    __builtin_amdgcn_s_setprio(1);
    #pragma unroll
    for (int dt = 0; dt < 2; ++dt)
        #pragma unroll
        for (int nj = 0; nj < 4; ++nj) {
            f32x4 acc = __builtin_amdgcn_mfma_f32_16x16x32_bf16(
                vf[dt][0], pf[nj][0], (f32x4){0.f, 0.f, 0.f, 0.f}, 0, 0, 0);
            o[dt][nj] = __builtin_amdgcn_mfma_f32_16x16x32_bf16(vf[dt][1], pf[nj][1], acc, 0, 0, 0);
        }
    __builtin_amdgcn_s_setprio(0);

    // all waves done with VT -> OL may overlay
    __syncthreads();
    #pragma unroll
    for (int nj = 0; nj < 4; ++nj) {
        const float rinv = 1.0f / rs[nj];
        const int row = 16 * nj + lr;
        const int swz = (row & 7) << 4;
        #pragma unroll
        for (int dt = 0; dt < 2; ++dt) {
            uint2 pk;
            pk.x = pk2(o[dt][nj][0] * rinv, o[dt][nj][1] * rinv);
            pk.y = pk2(o[dt][nj][2] * rinv, o[dt][nj][3] * rinv);
            *(uint2*)(OL + ((row * 512 + w * 64 + dt * 32 + lg * 8) ^ swz)) = pk;
        }
    }
    __syncthreads();
    // OL -> OWS [200704][256] bf16 (overlays V region, block-local rows)
    char* OWS = ws + OFF_V;
    #pragma unroll
    for (int it = 0; it < 4; ++it) {
        int c = it * 512 + t;
        if (c < 1568) {
            int tok = c >> 5, ch = c & 31;
            uint4 v = *(const uint4*)(OL + ((tok * 512 + ch * 16) ^ ((tok & 7) << 4)));
            *(uint4*)(OWS + ((int64_t)b * 49 + tok) * 512 + ch * 16) = v;
        }
    }
}

// ---------------------------------------------------------------------------
// proj GEMM: out[200704 x 256] = OWS[200704 x 256] @ wp^T + proj_b
// XCD-aware supertile dispatch: p = s*16 + j*8 + gm (16%8==0) -> both
// n-blocks of an m-tile share an XCD.
// ---------------------------------------------------------------------------
__global__ __launch_bounds__(256, 2) void proj_kernel(const float* __restrict__ proj_b,
                                                      float* __restrict__ out,
                                                      const char* __restrict__ ws) {
    __shared__ __align__(16) char smem[65536];
    uint16_t* A  = (uint16_t*)smem;             // [128][64] swz
    uint16_t* Bt = (uint16_t*)(smem + 16384);   // [128][64] swz
    const uint16_t* OWS = (const uint16_t*)(ws + OFF_V);
    const uint16_t* wp  = (const uint16_t*)(ws + OFF_WP);
    const int P = blockIdx.x;
    const int s = P / 16, r = P % 16;
    const int g = s * 8 + (r & 7);              // m-tile 0..1567
    const int m0 = g * 128, n0 = (r >> 3) * 128;
    const int t = threadIdx.x, l = t & 63, w = t >> 6;
    const int lr = l & 15, lg = l >> 4;
    const int wm = w >> 1, wn = w & 1;
    f32x4 acc[4][4];
    #pragma unroll
    for (int a = 0; a < 4; ++a)
        #pragma unroll
        for (int b2 = 0; b2 < 4; ++b2) acc[a][b2] = (f32x4){0.f, 0.f, 0.f, 0.f};

    for (int kk = 0; kk < 4; ++kk) {
        #pragma unroll
        for (int it = 0; it < 4; ++it) {
            int item = it * 256 + t;
            int rr = item >> 3, ch = item & 7;
            uint4 va = *(const uint4*)(OWS + (int64_t)(m0 + rr) * 256 + kk * 64 + ch * 8);
            *(uint4*)((char*)A + ((rr * 128 + ch * 16) ^ ((rr & 7) << 4))) = va;
            uint4 vb = *(const uint4*)(wp + (int64_t)(n0 + rr) * 256 + kk * 64 + ch * 8);
            *(uint4*)((char*)Bt + ((rr * 128 + ch * 16) ^ ((rr & 7) << 4))) = vb;
        }
        __syncthreads();
        #pragma unroll
        for (int kh = 0; kh < 2; ++kh) {
            bf16x8 af[4], bfr[4];
            #pragma unroll
            for (int mi = 0; mi < 4; ++mi) {
                int rr = wm * 64 + 16 * mi + lr;
                af[mi] = *(const bf16x8*)((char*)A + ((rr * 128 + kh * 64 + lg * 16) ^ ((rr & 7) << 4)));
            }
            #pragma unroll
            for (int nj = 0; nj < 4; ++nj) {
                int rr = wn * 64 + 16 * nj + lr;
                bfr[nj] = *(const bf16x8*)((char*)Bt + ((rr * 128 + kh * 64 + lg * 16) ^ ((rr & 7) << 4)));
            }
            #pragma unroll
            for (int nj = 0; nj < 4; ++nj)
                #pragma unroll
                for (int mi = 0; mi < 4; ++mi)
                    acc[nj][mi] = __builtin_amdgcn_mfma_f32_16x16x32_bf16(bfr[nj], af[mi], acc[nj][mi], 0, 0, 0);
        }
        __syncthreads();
    }
    // epilogue: C_LDS [128 tok][128 n] fp32 (overlay), swz; bias in copy-out
    float* C = (float*)smem;
    #pragma unroll
    for (int nj = 0; nj < 4; ++nj)
        #pragma unroll
        for (int mi = 0; mi < 4; ++mi) {
            int tok_l = wm * 64 + 16 * mi + lr;
            int nb = wn * 64 + 16 * nj + 4 * lg;
            *(f32x4*)((char*)C + ((tok_l * 512 + nb * 4) ^ ((tok_l & 7) << 4))) = acc[nj][mi];
        }
    __syncthreads();
    #pragma unroll
    for (int it = 0; it < 16; ++it) {
        int c = it * 256 + t;
        int mrow = c >> 5, ch = c & 31;
        f32x4 v = *(const f32x4*)((char*)C + ((mrow * 512 + ch * 16) ^ ((mrow & 7) << 4)));
        f32x4 bias = *(const f32x4*)(proj_b + n0 + ch * 4);
        v = v + bias;
        *(f32x4*)(out + (int64_t)(m0 + mrow) * 256 + n0 + ch * 4) = v;
    }
}

extern "C" void kernel_launch(void* const* d_in, const int* in_sizes, int n_in,
                              void* d_out, int out_size, void* d_ws, size_t ws_size,
                              hipStream_t stream) {
    const float* x          = (const float*)d_in[0];
    const float* qkv_w      = (const float*)d_in[1];
    const float* qkv_b      = (const float*)d_in[2];
    const float* proj_w     = (const float*)d_in[3];
    const float* proj_b     = (const float*)d_in[4];
    const float* bias_table = (const float*)d_in[5];
    const int*   rel_index  = (const int*)d_in[6];
    float* out = (float*)d_out;
    char*  ws  = (char*)d_ws;

    prep_kernel<<<1155, 256, 0, stream>>>(qkv_w, proj_w, qkv_b, bias_table, rel_index, ws);
    qkv_kernel<<<9408, 256, 0, stream>>>(x, ws);
    attn_kernel<<<NWIN, 512, 0, stream>>>(ws);
    proj_kernel<<<3136, 256, 0, stream>>>(proj_b, out, ws);
}

// Round 13
// 314.262 us; speedup vs baseline: 1.2855x; 1.0429x over previous
//
#include <hip/hip_runtime.h>
#include <hip/hip_bf16.h>
#include <stdint.h>

#define NWIN 4096

typedef __attribute__((ext_vector_type(8))) short bf16x8;
typedef __attribute__((ext_vector_type(4))) float f32x4;

// ws layout (bytes):
//   wq  bf16 [768][256]  @0         (plain, row-major, = qkv_w cast)
//   wp  bf16 [256][256]  @393216
//   rb  f32  [8][16][64][4] @524288 ([h][kt>>2][qt][kt&3], *1/ln2, kt>=49 -> -1e30)
//   wsb f32  [768]       @655360    (qkv_b plain)
//   Q   bf16 [4096*8][49][32] @OFF_Q ; K @OFF_K ; V @OFF_V
#define OFF_WQ 0LL
#define OFF_WP 393216LL
#define OFF_RB 524288LL
#define OFF_B  655360LL
#define OFF_Q  1048576LL
#define QKV_STRIDE 102760448LL
#define OFF_K  (OFF_Q + QKV_STRIDE)
#define OFF_V  (OFF_Q + 2 * QKV_STRIDE)

static __device__ __forceinline__ uint32_t f2bf(float f) {
    union { float f; uint32_t u; } v; v.f = f;
    return (v.u + 0x7FFFu + ((v.u >> 16) & 1u)) >> 16;
}

static __device__ __forceinline__ uint32_t pk2(float lo, float hi) {
    union { __hip_bfloat162 h; uint32_t u; } c;
    c.h = __float22bfloat162_rn(float2{lo, hi});
    return c.u;
}

union FragU { uint32_t u[4]; bf16x8 v; };

// ---------------------------------------------------------------------------
// prep: weights fp32->bf16 (plain), rb gather (*1/ln2, kt>=49 -> -1e30), bias
// ---------------------------------------------------------------------------
__global__ void prep_kernel(const float* __restrict__ qkv_w, const float* __restrict__ proj_w,
                            const float* __restrict__ qkv_b,
                            const float* __restrict__ bias_table, const int* __restrict__ rel_index,
                            char* __restrict__ ws) {
    uint16_t* wq  = (uint16_t*)(ws + OFF_WQ);
    uint16_t* wp  = (uint16_t*)(ws + OFF_WP);
    float*    rb  = (float*)(ws + OFF_RB);
    float*    wsb = (float*)(ws + OFF_B);
    const int total = 196608 + 65536 + 32768 + 768;
    for (int idx = blockIdx.x * blockDim.x + threadIdx.x; idx < total;
         idx += gridDim.x * blockDim.x) {
        if (idx < 196608) {
            wq[idx] = (uint16_t)f2bf(qkv_w[idx]);
        } else if (idx < 262144) {
            int i = idx - 196608;
            wp[i] = (uint16_t)f2bf(proj_w[i]);
        } else if (idx < 294912) {
            int i = idx - 262144;                 // [h][kt4][qt][ii]
            int h = i >> 12, kt4 = (i >> 8) & 15, qt = (i >> 2) & 63, ii = i & 3;
            int kt = kt4 * 4 + ii;
            float v = -1e30f;
            if (kt < 49 && qt < 49)
                v = bias_table[rel_index[qt * 49 + kt] * 8 + h] * 1.4426950408889634f;
            rb[i] = v;
        } else {
            int n = idx - 294912;
            wsb[n] = qkv_b[n];
        }
    }
}

// ---------------------------------------------------------------------------
// qkv GEMM: [200704 x 768] = x[200704 x 256] @ wq^T, 128x128 tiles, BK=64.
// XCD-aware supertile dispatch: p = s*48 + j*8 + gm  (48%8==0).
// ---------------------------------------------------------------------------
__global__ __launch_bounds__(256, 2) void qkv_kernel(const float* __restrict__ x,
                                                     char* __restrict__ ws) {
    __shared__ __align__(16) char smem[32768];
    uint16_t* A  = (uint16_t*)smem;             // [128][64] swz
    uint16_t* Bt = (uint16_t*)(smem + 16384);   // [128][64] swz
    const uint16_t* wq  = (const uint16_t*)(ws + OFF_WQ);
    const float*    wsb = (const float*)(ws + OFF_B);
    const int P = blockIdx.x;
    const int s = P / 48, r = P % 48;
    const int g = s * 8 + (r & 7);              // m-tile 0..1567
    const int m0 = g * 128, n0 = (r >> 3) * 128;
    const int t = threadIdx.x, l = t & 63, w = t >> 6;
    const int lr = l & 15, lg = l >> 4;
    const int wm = w >> 1, wn = w & 1;
    f32x4 acc[4][4];
    #pragma unroll
    for (int a = 0; a < 4; ++a)
        #pragma unroll
        for (int b2 = 0; b2 < 4; ++b2) acc[a][b2] = (f32x4){0.f, 0.f, 0.f, 0.f};

    for (int kk = 0; kk < 4; ++kk) {
        #pragma unroll
        for (int it = 0; it < 4; ++it) {                 // A: x fp32 -> bf16, swz
            int item = it * 256 + t;
            int rr = item >> 3, ch = item & 7;
            const float* src = x + (int64_t)(m0 + rr) * 256 + kk * 64 + ch * 8;
            float4 v0 = *(const float4*)src;
            float4 v1 = *(const float4*)(src + 4);
            uint4 pk;
            pk.x = pk2(v0.x, v0.y); pk.y = pk2(v0.z, v0.w);
            pk.z = pk2(v1.x, v1.y); pk.w = pk2(v1.z, v1.w);
            *(uint4*)((char*)A + ((rr * 128 + ch * 16) ^ ((rr & 7) << 4))) = pk;
        }
        #pragma unroll
        for (int it = 0; it < 4; ++it) {                 // B: wq bf16, swz
            int item = it * 256 + t;
            int rr = item >> 3, ch = item & 7;
            uint4 v = *(const uint4*)(wq + (int64_t)(n0 + rr) * 256 + kk * 64 + ch * 8);
            *(uint4*)((char*)Bt + ((rr * 128 + ch * 16) ^ ((rr & 7) << 4))) = v;
        }
        __syncthreads();
        #pragma unroll
        for (int kh = 0; kh < 2; ++kh) {
            bf16x8 af[4], bfr[4];
            #pragma unroll
            for (int mi = 0; mi < 4; ++mi) {
                int rr = wm * 64 + 16 * mi + lr;
                af[mi] = *(const bf16x8*)((char*)A + ((rr * 128 + kh * 64 + lg * 16) ^ ((rr & 7) << 4)));
            }
            #pragma unroll
            for (int nj = 0; nj < 4; ++nj) {
                int rr = wn * 64 + 16 * nj + lr;
                bfr[nj] = *(const bf16x8*)((char*)Bt + ((rr * 128 + kh * 64 + lg * 16) ^ ((rr & 7) << 4)));
            }
            #pragma unroll
            for (int nj = 0; nj < 4; ++nj)
                #pragma unroll
                for (int mi = 0; mi < 4; ++mi)
                    acc[nj][mi] = __builtin_amdgcn_mfma_f32_16x16x32_bf16(bfr[nj], af[mi], acc[nj][mi], 0, 0, 0);
        }
        __syncthreads();
    }
    // epilogue: bias + C_LDS [128 tok][128 n] bf16 (overlay A/B), swz by tok
    uint16_t* C = (uint16_t*)smem;
    #pragma unroll
    for (int nj = 0; nj < 4; ++nj) {
        f32x4 bias = *(const f32x4*)(wsb + n0 + wn * 64 + 16 * nj + 4 * lg);
        #pragma unroll
        for (int mi = 0; mi < 4; ++mi) {
            int tok_l = wm * 64 + 16 * mi + lr;
            int nb = wn * 64 + 16 * nj + 4 * lg;
            uint2 pk;
            pk.x = pk2(acc[nj][mi][0] + bias[0], acc[nj][mi][1] + bias[1]);
            pk.y = pk2(acc[nj][mi][2] + bias[2], acc[nj][mi][3] + bias[3]);
            *(uint2*)((char*)C + ((tok_l * 256 + nb * 2) ^ ((tok_l & 7) << 4))) = pk;
        }
    }
    __syncthreads();
    const int sel = n0 >> 8;
    char* dstBase = ws + OFF_Q + (int64_t)sel * QKV_STRIDE;
    #pragma unroll
    for (int it = 0; it < 8; ++it) {
        int hh = it >> 1;
        int mrow = ((it & 1) << 6) | (t >> 2);
        int q4 = t & 3;
        uint4 v = *(const uint4*)((char*)C + ((mrow * 256 + hh * 64 + q4 * 16) ^ ((mrow & 7) << 4)));
        int m = m0 + mrow;
        int b = m / 49;
        int tok = m - b * 49;
        int h = ((n0 >> 5) + hh) & 7;
        *(uint4*)(dstBase + (((int64_t)b * 8 + h) * 49 + tok) * 64 + q4 * 16) = v;
    }
}

// ---------------------------------------------------------------------------
// attn+proj fused: 1 block = 1 window, 8 waves = 8 heads; then r8 phase-G
// proj straight from the OL tile (no OWS round-trip).
// ---------------------------------------------------------------------------
__global__ __launch_bounds__(512, 2) void attn_kernel(const float* __restrict__ proj_b,
                                                      float* __restrict__ out,
                                                      const char* __restrict__ ws) {
    __shared__ __align__(16) char smem[32768];   // VT [8 heads][4096]; OL [64][256] swz overlays
    const int b = blockIdx.x;
    const int t = threadIdx.x, l = t & 63, w = t >> 6;
    const int lr = l & 15, lg = l >> 4;
    const uint16_t* Q = (const uint16_t*)(ws + OFF_Q);
    const uint16_t* K = (const uint16_t*)(ws + OFF_K);
    const uint16_t* V = (const uint16_t*)(ws + OFF_V);
    const uint16_t* wp = (const uint16_t*)(ws + OFF_WP);
    const float*   rb = (const float*)(ws + OFF_RB);
    char* VL = smem + w * 4096;
    char* OL = smem;
    const float scale = 0.17677669529663687f * 1.4426950408889634f;
    const int64_t bh = (int64_t)b * 8 + w;

    // issue v global loads early (consumed after softmax: T14 split)
    uint4 vstage[4];
    int   vc[4];
    #pragma unroll
    for (int it = 0; it < 4; ++it) {
        int item = it * 64 + l;
        int tok = item >> 2, d0 = (item & 3) * 8;
        int a = tok >> 4, g = (tok >> 2) & 3, ii = tok & 3;
        vc[it] = (a >> 1) * 32 + g * 8 + (a & 1) * 4 + ii;
        uint4 v = {0u, 0u, 0u, 0u};
        if (tok < 49) v = *(const uint4*)(V + (bh * 49 + tok) * 32 + d0);
        vstage[it] = v;
    }

    // q/k fragments (plain layout, rows = tokens)
    bf16x8 qf[4], kf[4];
    #pragma unroll
    for (int nj = 0; nj < 4; ++nj)
        qf[nj] = *(const bf16x8*)(Q + (bh * 49 + 16 * nj + lr) * 32 + lg * 8);
    #pragma unroll
    for (int mj = 0; mj < 4; ++mj)
        kf[mj] = *(const bf16x8*)(K + (bh * 49 + 16 * mj + lr) * 32 + lg * 8);

    // S^T, softmax (exp2), tau-pack pf  (round-8 verified)
    float rs[4];
    bf16x8 pf[4][2];
    #pragma unroll
    for (int nj = 0; nj < 4; ++nj) {
        f32x4 s[4];
        __builtin_amdgcn_s_setprio(1);
        #pragma unroll
        for (int mj = 0; mj < 4; ++mj)
            s[mj] = __builtin_amdgcn_mfma_f32_16x16x32_bf16(
                kf[mj], qf[nj], (f32x4){0.f, 0.f, 0.f, 0.f}, 0, 0, 0);
        __builtin_amdgcn_s_setprio(0);
        #pragma unroll
        for (int mj = 0; mj < 4; ++mj) {
            f32x4 rbv = *(const f32x4*)(rb + ((w * 16 + 4 * mj + lg) * 64 + 16 * nj + lr) * 4);
            s[mj] = s[mj] * scale + rbv;
        }
        float m = s[0][0];
        #pragma unroll
        for (int mj = 0; mj < 4; ++mj)
            #pragma unroll
            for (int i = 0; i < 4; ++i) m = fmaxf(m, s[mj][i]);
        m = fmaxf(m, __shfl_xor(m, 16));
        m = fmaxf(m, __shfl_xor(m, 32));
        float sum = 0.f;
        #pragma unroll
        for (int mj = 0; mj < 4; ++mj)
            #pragma unroll
            for (int i = 0; i < 4; ++i) {
                float e = __builtin_amdgcn_exp2f(s[mj][i] - m);
                s[mj][i] = e;
                sum += e;
            }
        sum += __shfl_xor(sum, 16);
        sum += __shfl_xor(sum, 32);
        rs[nj] = sum;
        #pragma unroll
        for (int ks = 0; ks < 2; ++ks) {
            FragU f;
            f.u[0] = pk2(s[2 * ks][0], s[2 * ks][1]);
            f.u[1] = pk2(s[2 * ks][2], s[2 * ks][3]);
            f.u[2] = pk2(s[2 * ks + 1][0], s[2 * ks + 1][1]);
            f.u[3] = pk2(s[2 * ks + 1][2], s[2 * ks + 1][3]);
            pf[nj][ks] = f.v;
        }
    }

    // scatter staged v -> VT[d][c] (swz), wave-local
    #pragma unroll
    for (int it = 0; it < 4; ++it) {
        int item = it * 64 + l;
        int d0 = (item & 3) * 8;
        int c = vc[it];
        const uint32_t words[4] = {vstage[it].x, vstage[it].y, vstage[it].z, vstage[it].w};
        #pragma unroll
        for (int jj = 0; jj < 4; ++jj) {
            int dA = d0 + 2 * jj, dB = dA + 1;
            *(uint16_t*)(VL + ((dA * 128 + c * 2) ^ ((dA & 7) << 4))) = (uint16_t)words[jj];
            *(uint16_t*)(VL + ((dB * 128 + c * 2) ^ ((dB & 7) << 4))) = (uint16_t)(words[jj] >> 16);
        }
    }
    // vf fragments: plain swizzled b128 reads, tau-consistent with pf
    bf16x8 vf[2][2];
    #pragma unroll
    for (int dt = 0; dt < 2; ++dt)
        #pragma unroll
        for (int ks = 0; ks < 2; ++ks) {
            int row = dt * 16 + lr;
            vf[dt][ks] = *(const bf16x8*)(VL + ((row * 128 + ks * 64 + lg * 16) ^ ((row & 7) << 4)));
        }

    // PV: O^T = V^T · P^T
    f32x4 o[2][4];
    __builtin_amdgcn_s_setprio(1);
    #pragma unroll
    for (int dt = 0; dt < 2; ++dt)
        #pragma unroll
        for (int nj = 0; nj < 4; ++nj) {
            f32x4 acc = __builtin_amdgcn_mfma_f32_16x16x32_bf16(
                vf[dt][0], pf[nj][0], (f32x4){0.f, 0.f, 0.f, 0.f}, 0, 0, 0);
            o[dt][nj] = __builtin_amdgcn_mfma_f32_16x16x32_bf16(vf[dt][1], pf[nj][1], acc, 0, 0, 0);
        }
    __builtin_amdgcn_s_setprio(0);

    // all waves done with VT -> OL may overlay
    __syncthreads();
    #pragma unroll
    for (int nj = 0; nj < 4; ++nj) {
        const float rinv = 1.0f / rs[nj];
        const int row = 16 * nj + lr;
        const int swz = (row & 7) << 4;
        #pragma unroll
        for (int dt = 0; dt < 2; ++dt) {
            uint2 pk;
            pk.x = pk2(o[dt][nj][0] * rinv, o[dt][nj][1] * rinv);
            pk.y = pk2(o[dt][nj][2] * rinv, o[dt][nj][3] * rinv);
            *(uint2*)(OL + ((row * 512 + w * 64 + dt * 32 + lg * 8) ^ swz)) = pk;
        }
    }
    __syncthreads();

    // ---- phase G (r8-verified): proj GEMM, wave w -> cols [w*32,w*32+32) ----
    f32x4 pacc[4][2];
    #pragma unroll
    for (int mi = 0; mi < 4; ++mi)
        #pragma unroll
        for (int nj = 0; nj < 2; ++nj)
            pacc[mi][nj] = (f32x4){0.f, 0.f, 0.f, 0.f};
    #pragma unroll
    for (int kk = 0; kk < 8; ++kk) {
        bf16x8 av[4];
        #pragma unroll
        for (int mi = 0; mi < 4; ++mi) {
            const int row = mi * 16 + lr;
            av[mi] = *(const bf16x8*)(OL + ((row * 512 + kk * 64 + lg * 16) ^ ((row & 7) << 4)));
        }
        #pragma unroll
        for (int nj = 0; nj < 2; ++nj) {
            bf16x8 bv = *(const bf16x8*)(wp + (w * 32 + nj * 16 + lr) * 256 + kk * 32 + lg * 8);
            #pragma unroll
            for (int mi = 0; mi < 4; ++mi)
                pacc[mi][nj] = __builtin_amdgcn_mfma_f32_16x16x32_bf16(av[mi], bv, pacc[mi][nj], 0, 0, 0);
        }
    }
    #pragma unroll
    for (int nj = 0; nj < 2; ++nj) {
        const int n = w * 32 + nj * 16 + lr;
        const float pb = proj_b[n];
        #pragma unroll
        for (int mi = 0; mi < 4; ++mi)
            #pragma unroll
            for (int i = 0; i < 4; ++i) {
                const int tok = mi * 16 + lg * 4 + i;
                if (tok < 49)
                    out[((int64_t)b * 49 + tok) * 256 + n] = pacc[mi][nj][i] + pb;
            }
    }
}

extern "C" void kernel_launch(void* const* d_in, const int* in_sizes, int n_in,
                              void* d_out, int out_size, void* d_ws, size_t ws_size,
                              hipStream_t stream) {
    const float* x          = (const float*)d_in[0];
    const float* qkv_w      = (const float*)d_in[1];
    const float* qkv_b      = (const float*)d_in[2];
    const float* proj_w     = (const float*)d_in[3];
    const float* proj_b     = (const float*)d_in[4];
    const float* bias_table = (const float*)d_in[5];
    const int*   rel_index  = (const int*)d_in[6];
    float* out = (float*)d_out;
    char*  ws  = (char*)d_ws;

    prep_kernel<<<1155, 256, 0, stream>>>(qkv_w, proj_w, qkv_b, bias_table, rel_index, ws);
    qkv_kernel<<<9408, 256, 0, stream>>>(x, ws);
    attn_kernel<<<NWIN, 512, 0, stream>>>(proj_b, out, ws);
}